// Round 9
// baseline (124.987 us; speedup 1.0000x reference)
//
#include <hip/hip_runtime.h>

#define BB 4
#define MM 128
#define LL 512
#define DD 768
#define NEGF (-1e30f)
#define REPS 5
#define HALF4 ((size_t)BB * MM * DD / 4)   // float4s per lh partial

// DIAGNOSTIC + CANDIDATE: r5 structure (256 thr = 4 waves, float4/lane,
// 768 blocks = 3/CU), but the core is FULL INLINE ASM with an exactly known
// stream: per (2l x 4d) site = 4 SALU select + 8 v_add_f32 + 4 v_max3_f32
// (1.5 VALU/elem guaranteed, no compiler bloat possible). REPS=5 repeats the
// whole computation (asm memory clobber kills cross-rep CSE) so the kernel
// shows up in the top-5 counter rows; every rep writes the same partials, the
// merge kernel reduces the 4 lh regions -> output identical to r5.
__global__ __launch_bounds__(256, 3) void mention_max_part(
    const float* __restrict__ h, const int* __restrict__ mask,
    float* __restrict__ ws)
{
    const int lane = threadIdx.x & 63;
    const int wave = threadIdx.x >> 6;     // 0..3
    const int dch  = blockIdx.x;           // 0..2
    const int mch  = blockIdx.y >> 2;      // 0..15
    const int lh   = blockIdx.y & 3;       // 0..3
    const int b    = blockIdx.z;           // 0..3

    const int m0 = mch * 8;
    const int l0 = lh * 128 + wave * 32;   // wave owns [l0, l0+32)

    const int lclamp = (l0 + lane < LL) ? (l0 + lane) : (LL - 1);
    const int* mp = mask + ((size_t)(b * MM + m0)) * LL + lclamp;

    const unsigned negb = __float_as_uint(NEGF);
    __shared__ float4 red[4][8][64];       // 32 KB

#pragma unroll 1
    for (int rep = 0; rep < REPS; ++rep) {
        asm volatile("" ::: "memory");     // full reload/recompute per rep

        unsigned w32[8];
#pragma unroll
        for (int m = 0; m < 8; ++m) {
            unsigned long long bl = __ballot(mp[m * LL] != 0);
            w32[m] = (unsigned)__builtin_amdgcn_readfirstlane((int)(unsigned)bl);
        }

        float accx[8], accy[8], accz[8], accw[8];
#pragma unroll
        for (int m = 0; m < 8; ++m) {
            accx[m] = NEGF; accy[m] = NEGF; accz[m] = NEGF; accw[m] = NEGF;
        }

#pragma unroll
        for (int s = 0; s < 2; ++s) {
            // Stage 16 rows x float4 (64 VGPR), coalesced 1KB/row-instr.
            float4 hreg[16];
#pragma unroll
            for (int i = 0; i < 16; ++i)
                hreg[i] = ((const float4*)h)[
                    (size_t)(b * LL + l0 + s * 16 + i) * (DD / 4) + dch * 64 + lane];

#pragma unroll
            for (int m = 0; m < 8; ++m) {
                const unsigned w = w32[m];
#pragma unroll
                for (int i = 0; i < 16; i += 2) {
                    const int k = s * 16 + i;
                    unsigned adu0, adu1;
                    asm("s_bitcmp1_b32 %2, %3\n\t"
                        "s_cselect_b32 %0, 0, %4\n\t"
                        "s_bitcmp1_b32 %2, %5\n\t"
                        "s_cselect_b32 %1, 0, %4"
                        : "=&s"(adu0), "=&s"(adu1)
                        : "s"(w), "i"(k), "s"(negb), "i"(k + 1)
                        : "scc");
                    const float ad0 = __uint_as_float(adu0);
                    const float ad1 = __uint_as_float(adu1);
                    float t0, t1, t2, t3, t4, t5, t6, t7;
                    asm("v_add_f32 %0, %20, %12\n\t"
                        "v_add_f32 %1, %20, %13\n\t"
                        "v_add_f32 %2, %20, %14\n\t"
                        "v_add_f32 %3, %20, %15\n\t"
                        "v_add_f32 %4, %21, %16\n\t"
                        "v_add_f32 %5, %21, %17\n\t"
                        "v_add_f32 %6, %21, %18\n\t"
                        "v_add_f32 %7, %21, %19\n\t"
                        "v_max3_f32 %8, %0, %4, %8\n\t"
                        "v_max3_f32 %9, %1, %5, %9\n\t"
                        "v_max3_f32 %10, %2, %6, %10\n\t"
                        "v_max3_f32 %11, %3, %7, %11"
                        : "=&v"(t0), "=&v"(t1), "=&v"(t2), "=&v"(t3),
                          "=&v"(t4), "=&v"(t5), "=&v"(t6), "=&v"(t7),
                          "+v"(accx[m]), "+v"(accy[m]), "+v"(accz[m]), "+v"(accw[m])
                        : "v"(hreg[i].x), "v"(hreg[i].y),
                          "v"(hreg[i].z), "v"(hreg[i].w),
                          "v"(hreg[i + 1].x), "v"(hreg[i + 1].y),
                          "v"(hreg[i + 1].z), "v"(hreg[i + 1].w),
                          "s"(ad0), "s"(ad1));
                }
            }
        }

#pragma unroll
        for (int m = 0; m < 8; ++m)
            red[wave][m][lane] = make_float4(accx[m], accy[m], accz[m], accw[m]);
        __syncthreads();

#pragma unroll
        for (int r = 0; r < 2; ++r) {
            const int o  = (int)threadIdx.x + r * 256;  // 0..511
            const int m  = o >> 6;
            const int dp = o & 63;
            float4 v = red[0][m][dp];
#pragma unroll
            for (int wv = 1; wv < 4; ++wv) {
                const float4 u = red[wv][m][dp];
                v.x = fmaxf(v.x, u.x);
                v.y = fmaxf(v.y, u.y);
                v.z = fmaxf(v.z, u.z);
                v.w = fmaxf(v.w, u.w);
            }
            // ws layout: [lh][b][m][d] (all reps write identical values)
            ((float4*)ws)[(size_t)lh * HALF4 +
                          (size_t)(b * MM + m0 + m) * (DD / 4) + dch * 64 + dp] = v;
        }
        __syncthreads();                   // WAR on red before next rep
    }
}

// Merge the 4 lh partials -> out.
__global__ __launch_bounds__(256) void mention_max_merge(
    const float* __restrict__ ws, float* __restrict__ out)
{
    const int i = (int)(blockIdx.x * blockDim.x + threadIdx.x);  // float4 idx
    float4 v = ((const float4*)ws)[i];
#pragma unroll
    for (int p = 1; p < 4; ++p) {
        const float4 u = ((const float4*)ws)[(size_t)p * HALF4 + i];
        v.x = fmaxf(v.x, u.x);
        v.y = fmaxf(v.y, u.y);
        v.z = fmaxf(v.z, u.z);
        v.w = fmaxf(v.w, u.w);
    }
    ((float4*)out)[i] = v;
}

extern "C" void kernel_launch(void* const* d_in, const int* in_sizes, int n_in,
                              void* d_out, int out_size, void* d_ws, size_t ws_size,
                              hipStream_t stream) {
    const float* h    = (const float*)d_in[0];
    const int*   mask = (const int*)d_in[1];
    float*       out  = (float*)d_out;
    float*       ws   = (float*)d_ws;
    dim3 grid1(DD / 256, (MM / 8) * 4, BB);
    mention_max_part<<<grid1, dim3(256), 0, stream>>>(h, mask, ws);
    const int n4 = BB * MM * DD / 4;       // 98304 float4
    mention_max_merge<<<n4 / 256, dim3(256), 0, stream>>>(ws, out);
}

// Round 10
// 75.171 us; speedup vs baseline: 1.6627x; 1.6627x over previous
//
#include <hip/hip_runtime.h>

#define BB 4
#define MM 128
#define LL 512
#define DD 768
#define NEGF (-1e30f)
#define HALF4 ((size_t)BB * MM * DD / 4)   // float4s per lh partial

// Monotone float<->uint encode for unsigned ds_max reduction (bijective).
__device__ __forceinline__ unsigned enc(float x) {
    int b = __float_as_int(x);
    return (unsigned)(b ^ ((b >> 31) | 0x80000000));
}
__device__ __forceinline__ float dec(unsigned u) {
    int b = (u & 0x80000000u) ? (int)(u ^ 0x80000000u) : ~(int)u;
    return __int_as_float(b);
}

// Kernel1: 256 thr = 4 waves. Grid (3 dch, 8 mch x 8 lh, 4 b) = 768 blocks
// = 3 blocks/CU, 12 waves/CU. Block owns 16 m x 64 l x 256 d; wave owns 16 l
// (16 rows x float4 staged = 64 VGPR; acc 16 m x float4 = 64 VGPR).
// KEY CHANGE vs r9: row-pair loop is OUTER, m-loop INNER -> consumption order
// matches load order -> compiler emits stepped vmcnt (pipelined) instead of a
// full vmcnt(0) drain; plus 16 m/block halves redundant h L2 traffic.
// Core per (2l x 4d x m) site: 4 SALU select + 8 v_add + 4 v_max3 (asm, exact
// reference arithmetic). Cross-wave reduce: encoded ds_max (16 KB LDS).
__global__ __launch_bounds__(256, 3) void mention_max_part(
    const float* __restrict__ h, const int* __restrict__ mask,
    float* __restrict__ ws)
{
    const int lane = threadIdx.x & 63;
    const int wave = threadIdx.x >> 6;     // 0..3
    const int dch  = blockIdx.x;           // 0..2
    const int mch  = blockIdx.y >> 3;      // 0..7
    const int lh   = blockIdx.y & 7;       // 0..7
    const int b    = blockIdx.z;           // 0..3

    const int q  = lane >> 4;              // 0..3 : m sub-group
    const int lb = lane & 15;              // l offset within wave's 16 rows
    const int m0 = mch * 16;
    const int l0 = lh * 64 + wave * 16;    // wave owns [l0, l0+16)

    __shared__ unsigned red[16][4][64];    // 16 KB, comp-split
    for (int t = (int)threadIdx.x; t < 16 * 4 * 64; t += 256)
        ((unsigned*)red)[t] = 0u;          // 0 < enc(-1e30): safe floor

    // Mask loads + ballots first (their vmcnt retires before h rows).
    const int* mp = mask + ((size_t)(b * MM + m0 + q)) * LL + l0 + lb;
    unsigned w16[16];
#pragma unroll
    for (int r = 0; r < 4; ++r) {
        const unsigned long long bal = __ballot(mp[r * 4 * LL] != 0);
        const unsigned ulo = (unsigned)bal, uhi = (unsigned)(bal >> 32);
        w16[r * 4 + 0] = (unsigned)__builtin_amdgcn_readfirstlane((int)(ulo & 0xFFFFu));
        w16[r * 4 + 1] = (unsigned)__builtin_amdgcn_readfirstlane((int)(ulo >> 16));
        w16[r * 4 + 2] = (unsigned)__builtin_amdgcn_readfirstlane((int)(uhi & 0xFFFFu));
        w16[r * 4 + 3] = (unsigned)__builtin_amdgcn_readfirstlane((int)(uhi >> 16));
    }

    // Issue all 16 row loads up front (row i consumed at pair i>>1).
    float4 hreg[16];
#pragma unroll
    for (int i = 0; i < 16; ++i)
        hreg[i] = ((const float4*)h)[
            (size_t)(b * LL + l0 + i) * (DD / 4) + dch * 64 + lane];

    const unsigned negb = __float_as_uint(NEGF);

    float accx[16], accy[16], accz[16], accw[16];
#pragma unroll
    for (int m = 0; m < 16; ++m) {
        accx[m] = NEGF; accy[m] = NEGF; accz[m] = NEGF; accw[m] = NEGF;
    }

    // Pair-outer / m-inner: consumption order == load order.
#pragma unroll
    for (int i = 0; i < 16; i += 2) {
#pragma unroll
        for (int m = 0; m < 16; ++m) {
            const unsigned w = w16[m];
            unsigned adu0, adu1;
            asm("s_bitcmp1_b32 %2, %3\n\t"
                "s_cselect_b32 %0, 0, %4\n\t"
                "s_bitcmp1_b32 %2, %5\n\t"
                "s_cselect_b32 %1, 0, %4"
                : "=&s"(adu0), "=&s"(adu1)
                : "s"(w), "i"(i), "s"(negb), "i"(i + 1)
                : "scc");
            const float ad0 = __uint_as_float(adu0);
            const float ad1 = __uint_as_float(adu1);
            float t0, t1, t2, t3, t4, t5, t6, t7;
            asm("v_add_f32 %0, %20, %12\n\t"
                "v_add_f32 %1, %20, %13\n\t"
                "v_add_f32 %2, %20, %14\n\t"
                "v_add_f32 %3, %20, %15\n\t"
                "v_add_f32 %4, %21, %16\n\t"
                "v_add_f32 %5, %21, %17\n\t"
                "v_add_f32 %6, %21, %18\n\t"
                "v_add_f32 %7, %21, %19\n\t"
                "v_max3_f32 %8, %0, %4, %8\n\t"
                "v_max3_f32 %9, %1, %5, %9\n\t"
                "v_max3_f32 %10, %2, %6, %10\n\t"
                "v_max3_f32 %11, %3, %7, %11"
                : "=&v"(t0), "=&v"(t1), "=&v"(t2), "=&v"(t3),
                  "=&v"(t4), "=&v"(t5), "=&v"(t6), "=&v"(t7),
                  "+v"(accx[m]), "+v"(accy[m]), "+v"(accz[m]), "+v"(accw[m])
                : "v"(hreg[i].x), "v"(hreg[i].y),
                  "v"(hreg[i].z), "v"(hreg[i].w),
                  "v"(hreg[i + 1].x), "v"(hreg[i + 1].y),
                  "v"(hreg[i + 1].z), "v"(hreg[i + 1].w),
                  "s"(ad0), "s"(ad1));
        }
    }

    __syncthreads();                       // red init visible
#pragma unroll
    for (int m = 0; m < 16; ++m) {
        atomicMax(&red[m][0][lane], enc(accx[m]));
        atomicMax(&red[m][1][lane], enc(accy[m]));
        atomicMax(&red[m][2][lane], enc(accz[m]));
        atomicMax(&red[m][3][lane], enc(accw[m]));
    }
    __syncthreads();

    // Block outputs: 16 m x 256 d = 1024 float4; 4 per thread -> ws[lh][...]
#pragma unroll
    for (int r = 0; r < 4; ++r) {
        const int o  = (int)threadIdx.x + r * 256;  // 0..1023
        const int m  = o >> 6;
        const int dp = o & 63;
        float4 v;
        v.x = dec(red[m][0][dp]);
        v.y = dec(red[m][1][dp]);
        v.z = dec(red[m][2][dp]);
        v.w = dec(red[m][3][dp]);
        ((float4*)ws)[(size_t)lh * HALF4 +
                      (size_t)(b * MM + m0 + m) * (DD / 4) + dch * 64 + dp] = v;
    }
}

// Kernel2: out = elementwise max of the 8 lh partials.
__global__ __launch_bounds__(256) void mention_max_merge(
    const float* __restrict__ ws, float* __restrict__ out)
{
    const int i = (int)(blockIdx.x * blockDim.x + threadIdx.x);  // float4 idx
    float4 v = ((const float4*)ws)[i];
#pragma unroll
    for (int p = 1; p < 8; ++p) {
        const float4 u = ((const float4*)ws)[(size_t)p * HALF4 + i];
        v.x = fmaxf(v.x, u.x);
        v.y = fmaxf(v.y, u.y);
        v.z = fmaxf(v.z, u.z);
        v.w = fmaxf(v.w, u.w);
    }
    ((float4*)out)[i] = v;
}

extern "C" void kernel_launch(void* const* d_in, const int* in_sizes, int n_in,
                              void* d_out, int out_size, void* d_ws, size_t ws_size,
                              hipStream_t stream) {
    const float* h    = (const float*)d_in[0];
    const int*   mask = (const int*)d_in[1];
    float*       out  = (float*)d_out;
    float*       ws   = (float*)d_ws;
    dim3 grid1(DD / 256, 8 * 8, BB);
    mention_max_part<<<grid1, dim3(256), 0, stream>>>(h, mask, ws);
    const int n4 = BB * MM * DD / 4;       // 98304 float4
    mention_max_merge<<<n4 / 256, dim3(256), 0, stream>>>(ws, out);
}

// Round 11
// 74.144 us; speedup vs baseline: 1.6857x; 1.0139x over previous
//
#include <hip/hip_runtime.h>

#define BB 4
#define MM 128
#define LL 512
#define DD 768
#define NEGF (-1e30f)
#define HALF4 ((size_t)BB * MM * DD / 4)   // float4s per lh partial

// One (2l x 4d) site for all 8 m: selects on the SCALAR pipe with DYNAMIC
// bit index (SGPR), core exactly 8 v_add + 4 v_max3 per m. Inline asm so the
// stream is known; called from a ROLLED loop so the body stays ~1 KB.
__device__ __forceinline__ void site8(
    const unsigned (&w32)[8], int i, int ip1, unsigned negb,
    const float4& c0, const float4& c1,
    float (&accx)[8], float (&accy)[8], float (&accz)[8], float (&accw)[8])
{
#pragma unroll
    for (int m = 0; m < 8; ++m) {
        unsigned adu0, adu1;
        asm("s_bitcmp1_b32 %2, %3\n\t"
            "s_cselect_b32 %0, 0, %4\n\t"
            "s_bitcmp1_b32 %2, %5\n\t"
            "s_cselect_b32 %1, 0, %4"
            : "=&s"(adu0), "=&s"(adu1)
            : "s"(w32[m]), "s"(i), "s"(negb), "s"(ip1)
            : "scc");
        const float ad0 = __uint_as_float(adu0);
        const float ad1 = __uint_as_float(adu1);
        float t0, t1, t2, t3, t4, t5, t6, t7;
        asm("v_add_f32 %0, %20, %12\n\t"
            "v_add_f32 %1, %20, %13\n\t"
            "v_add_f32 %2, %20, %14\n\t"
            "v_add_f32 %3, %20, %15\n\t"
            "v_add_f32 %4, %21, %16\n\t"
            "v_add_f32 %5, %21, %17\n\t"
            "v_add_f32 %6, %21, %18\n\t"
            "v_add_f32 %7, %21, %19\n\t"
            "v_max3_f32 %8, %0, %4, %8\n\t"
            "v_max3_f32 %9, %1, %5, %9\n\t"
            "v_max3_f32 %10, %2, %6, %10\n\t"
            "v_max3_f32 %11, %3, %7, %11"
            : "=&v"(t0), "=&v"(t1), "=&v"(t2), "=&v"(t3),
              "=&v"(t4), "=&v"(t5), "=&v"(t6), "=&v"(t7),
              "+v"(accx[m]), "+v"(accy[m]), "+v"(accz[m]), "+v"(accw[m])
            : "v"(c0.x), "v"(c0.y), "v"(c0.z), "v"(c0.w),
              "v"(c1.x), "v"(c1.y), "v"(c1.z), "v"(c1.w),
              "s"(ad0), "s"(ad1));
    }
}

// Kernel1: r5 geometry -- 256 thr = 4 waves, grid (3 dch, 16 mch x 4 lh, 4 b)
// = 768 blocks = 3/CU, 12 waves/CU. Wave owns 32 l, lane holds float4 of d.
// SINGLE CHANGE vs r9: the l-loop is ROLLED (#pragma unroll 1, 2-row software
// pipeline) -> body ~1.2 KB instead of ~20 KB straight-line. Tests and, if
// the I$-fetch theory is right, removes the instruction-fetch wall.
__global__ __launch_bounds__(256, 3) void mention_max_part(
    const float* __restrict__ h, const int* __restrict__ mask,
    float* __restrict__ ws)
{
    const int lane = threadIdx.x & 63;
    const int wave = threadIdx.x >> 6;     // 0..3
    const int dch  = blockIdx.x;           // 0..2
    const int mch  = blockIdx.y >> 2;      // 0..15
    const int lh   = blockIdx.y & 3;       // 0..3
    const int b    = blockIdx.z;           // 0..3

    const int m0 = mch * 8;
    const int l0 = lh * 128 + wave * 32;   // wave owns [l0, l0+32)

    // lane->l mask pointer, clamped in-bounds (ballot bits >=32 unused).
    const int lclamp = (l0 + lane < LL) ? (l0 + lane) : (LL - 1);
    const int* mp = mask + ((size_t)(b * MM + m0)) * LL + lclamp;

    unsigned w32[8];
#pragma unroll
    for (int m = 0; m < 8; ++m) {
        unsigned long long bl = __ballot(mp[m * LL] != 0);
        w32[m] = (unsigned)__builtin_amdgcn_readfirstlane((int)(unsigned)bl);
    }

    const unsigned negb = __float_as_uint(NEGF);

    float accx[8], accy[8], accz[8], accw[8];
#pragma unroll
    for (int m = 0; m < 8; ++m) {
        accx[m] = NEGF; accy[m] = NEGF; accz[m] = NEGF; accw[m] = NEGF;
    }

    const size_t st = DD / 4;              // float4 row stride
    const float4* hp = (const float4*)h +
                       (size_t)(b * LL + l0) * st + dch * 64 + lane;

    // Software-pipelined rolled loop: current pair (c0,c1), prefetch (n0,n1).
    float4 c0 = hp[0];
    float4 c1 = hp[st];
#pragma unroll 1
    for (int i = 0; i < 30; i += 2) {
        const float4 n0 = hp[2 * st];
        const float4 n1 = hp[3 * st];
        hp += 2 * st;
        site8(w32, i, i + 1, negb, c0, c1, accx, accy, accz, accw);
        c0 = n0;
        c1 = n1;
    }
    site8(w32, 30, 31, negb, c0, c1, accx, accy, accz, accw);

    // Cross-wave tree reduce (proven conflict-free layout).
    __shared__ float4 red[4][8][64];       // 32 KB
#pragma unroll
    for (int m = 0; m < 8; ++m)
        red[wave][m][lane] = make_float4(accx[m], accy[m], accz[m], accw[m]);
    __syncthreads();

#pragma unroll
    for (int r = 0; r < 2; ++r) {
        const int o  = (int)threadIdx.x + r * 256;  // 0..511
        const int m  = o >> 6;
        const int dp = o & 63;
        float4 v = red[0][m][dp];
#pragma unroll
        for (int wv = 1; wv < 4; ++wv) {
            const float4 u = red[wv][m][dp];
            v.x = fmaxf(v.x, u.x);
            v.y = fmaxf(v.y, u.y);
            v.z = fmaxf(v.z, u.z);
            v.w = fmaxf(v.w, u.w);
        }
        // ws layout: [lh][b][m][d]
        ((float4*)ws)[(size_t)lh * HALF4 +
                      (size_t)(b * MM + m0 + m) * (DD / 4) + dch * 64 + dp] = v;
    }
}

// Kernel2: out = elementwise max of the 4 lh partials.
__global__ __launch_bounds__(256) void mention_max_merge(
    const float* __restrict__ ws, float* __restrict__ out)
{
    const int i = (int)(blockIdx.x * blockDim.x + threadIdx.x);  // float4 idx
    float4 v = ((const float4*)ws)[i];
#pragma unroll
    for (int p = 1; p < 4; ++p) {
        const float4 u = ((const float4*)ws)[(size_t)p * HALF4 + i];
        v.x = fmaxf(v.x, u.x);
        v.y = fmaxf(v.y, u.y);
        v.z = fmaxf(v.z, u.z);
        v.w = fmaxf(v.w, u.w);
    }
    ((float4*)out)[i] = v;
}

extern "C" void kernel_launch(void* const* d_in, const int* in_sizes, int n_in,
                              void* d_out, int out_size, void* d_ws, size_t ws_size,
                              hipStream_t stream) {
    const float* h    = (const float*)d_in[0];
    const int*   mask = (const int*)d_in[1];
    float*       out  = (float*)d_out;
    float*       ws   = (float*)d_ws;
    dim3 grid1(DD / 256, (MM / 8) * 4, BB);
    mention_max_part<<<grid1, dim3(256), 0, stream>>>(h, mask, ws);
    const int n4 = BB * MM * DD / 4;       // 98304 float4
    mention_max_merge<<<n4 / 256, dim3(256), 0, stream>>>(ws, out);
}